// Round 1
// baseline (775.084 us; speedup 1.0000x reference)
//
#include <hip/hip_runtime.h>

// SwinStyleAttention fused kernel — MI355X gfx950
// Block = 1 window (64 tokens x 128 ch), 4 waves = 4 heads.
// MFMA 16x16x32 bf16 throughout; fp32 accumulate; softmax in-register.

typedef __attribute__((ext_vector_type(8))) short bf16x8;   // 8 bf16 = 4 VGPRs
typedef __attribute__((ext_vector_type(4))) float f32x4;    // MFMA 16x16 acc

__device__ __forceinline__ unsigned short f2bf(float f) {
  union { float f; unsigned u; } v; v.f = f;
  return (unsigned short)((v.u + 0x7FFFu + ((v.u >> 16) & 1u)) >> 16);  // RNE
}

// Weight prep: wqkvT[384][128] then wprojT[128][128], bf16, B^T layout in ws.
__global__ void prep_kernel(const float* __restrict__ wqkv,
                            const float* __restrict__ wproj,
                            unsigned short* __restrict__ wT) {
  const int idx = blockIdx.x * 256 + (int)threadIdx.x;   // 65536 total
  if (idx < 384 * 128) {
    const int n = idx >> 7, k = idx & 127;
    wT[idx] = f2bf(wqkv[k * 384 + n]);
  } else {
    const int j = idx - 384 * 128;
    const int n = j >> 7, k = j & 127;
    wT[idx] = f2bf(wproj[k * 128 + n]);
  }
}

// LDS map (elements of unsigned short, total 29696 el = 59392 B):
//   [0,9216)        : Xs[64][136]  (phase 0-1)  -> Vt 4x[32][72] (ph 1b-3) -> Os[64][136] (ph 3b-4)
//   [9216+h*5120 ..): per-head Q[64][40], K[64][40];  P[64][72] overlays Q+K after frags read.
__global__ void __launch_bounds__(256, 2)
swin_kernel(const float* __restrict__ x, const unsigned short* __restrict__ wT,
            const float* __restrict__ bproj, float* __restrict__ out) {
  __shared__ unsigned short SM[29696];

  const int win = blockIdx.x;
  const int b   = win >> 10;
  const int wy  = (win >> 5) & 31;
  const int wx  = win & 31;
  const int tid  = (int)threadIdx.x;
  const int lane = tid & 63;
  const int wv   = tid >> 6;        // wave id == head id
  const int l16  = lane & 15;
  const int quad = lane >> 4;

  unsigned short* Xs = SM;                        // stride 136
  unsigned short* Vt = SM + wv * 2304;            // stride 72, 32 rows (overlay on Xs)
  unsigned short* Qs = SM + 9216 + wv * 5120;     // stride 40
  unsigned short* Ks = Qs + 2560;                 // stride 40
  unsigned short* Ps = Qs;                        // stride 72 (overlay on Q+K)

  // ---- Phase 0: gather shifted window, fp32 -> bf16 -> Xs[token][ch] ----
  {
    const int t4  = tid & 15;          // token group of 4 (same h-row run)
    const int cw  = tid >> 4;          // channel subgroup
    const int ty  = t4 >> 1;
    const int txb = (t4 & 1) << 2;
    const int hh  = (wy * 8 + ty + 4) & 255;     // roll(-4): src = dst+4 mod 256
    const int ww  = (wx * 8 + txb + 4) & 255;    // multiple of 4 -> no wrap in float4
    const float* src = x + ((b * 128) * 256 + hh) * 256 + ww;
    const int t0 = t4 << 2;
#pragma unroll
    for (int i = 0; i < 8; ++i) {
      const int c = i * 16 + cw;
      const float4 v = *(const float4*)(src + c * 65536);
      Xs[(t0 + 0) * 136 + c] = f2bf(v.x);
      Xs[(t0 + 1) * 136 + c] = f2bf(v.y);
      Xs[(t0 + 2) * 136 + c] = f2bf(v.z);
      Xs[(t0 + 3) * 136 + c] = f2bf(v.w);
    }
  }
  __syncthreads();

  // ---- Phase 1: QKV GEMM for head wv: [64x128] @ [128x32] x3 ----
  f32x4 aQ[4][2] = {}, aK[4][2] = {}, aV[4][2] = {};
#pragma unroll
  for (int ks = 0; ks < 4; ++ks) {
    const int ko = ks * 32 + quad * 8;
    bf16x8 af[4];
#pragma unroll
    for (int mt = 0; mt < 4; ++mt)
      af[mt] = *(const bf16x8*)&Xs[(mt * 16 + l16) * 136 + ko];
#pragma unroll
    for (int nt = 0; nt < 2; ++nt) {
      const int n = wv * 32 + nt * 16 + l16;
      const bf16x8 bq = *(const bf16x8*)&wT[n * 128 + ko];
      const bf16x8 bk = *(const bf16x8*)&wT[(128 + n) * 128 + ko];
      const bf16x8 bv = *(const bf16x8*)&wT[(256 + n) * 128 + ko];
#pragma unroll
      for (int mt = 0; mt < 4; ++mt) {
        aQ[mt][nt] = __builtin_amdgcn_mfma_f32_16x16x32_bf16(af[mt], bq, aQ[mt][nt], 0, 0, 0);
        aK[mt][nt] = __builtin_amdgcn_mfma_f32_16x16x32_bf16(af[mt], bk, aK[mt][nt], 0, 0, 0);
        aV[mt][nt] = __builtin_amdgcn_mfma_f32_16x16x32_bf16(af[mt], bv, aV[mt][nt], 0, 0, 0);
      }
    }
  }
  __syncthreads();   // all Xs reads done -> Vt may overlay Xs region

  // ---- Phase 1b: stage Q (pre-scaled), K row-major; V transposed ----
#pragma unroll
  for (int mt = 0; mt < 4; ++mt)
#pragma unroll
    for (int nt = 0; nt < 2; ++nt)
#pragma unroll
      for (int r = 0; r < 4; ++r) {
        const int row = mt * 16 + quad * 4 + r;   // token (verified C/D map)
        const int col = nt * 16 + l16;            // dh
        Qs[row * 40 + col] = f2bf(aQ[mt][nt][r] * 0.17677669529663687f);
        Ks[row * 40 + col] = f2bf(aK[mt][nt][r]);
        Vt[col * 72 + row] = f2bf(aV[mt][nt][r]); // V^T for PV B-operand
      }

  // ---- Phase 2: S = Q K^T (64x64, K=32 in one MFMA step), softmax ----
  bf16x8 qf[4], kf[4];
#pragma unroll
  for (int mt = 0; mt < 4; ++mt) qf[mt] = *(const bf16x8*)&Qs[(mt * 16 + l16) * 40 + quad * 8];
#pragma unroll
  for (int nt = 0; nt < 4; ++nt) kf[nt] = *(const bf16x8*)&Ks[(nt * 16 + l16) * 40 + quad * 8];
  f32x4 aS[4][4] = {};
#pragma unroll
  for (int mt = 0; mt < 4; ++mt)
#pragma unroll
    for (int nt = 0; nt < 4; ++nt)
      aS[mt][nt] = __builtin_amdgcn_mfma_f32_16x16x32_bf16(qf[mt], kf[nt], aS[mt][nt], 0, 0, 0);

  // each S row lives in one 16-lane quad (4 vals/lane) -> shfl_xor reduce
#pragma unroll
  for (int mt = 0; mt < 4; ++mt)
#pragma unroll
    for (int r = 0; r < 4; ++r) {
      const float s0 = aS[mt][0][r], s1 = aS[mt][1][r], s2 = aS[mt][2][r], s3 = aS[mt][3][r];
      float m = fmaxf(fmaxf(s0, s1), fmaxf(s2, s3));
      m = fmaxf(m, __shfl_xor(m, 1, 16));
      m = fmaxf(m, __shfl_xor(m, 2, 16));
      m = fmaxf(m, __shfl_xor(m, 4, 16));
      m = fmaxf(m, __shfl_xor(m, 8, 16));
      const float e0 = __expf(s0 - m), e1 = __expf(s1 - m), e2 = __expf(s2 - m), e3 = __expf(s3 - m);
      float t = e0 + e1 + e2 + e3;
      t += __shfl_xor(t, 1, 16);
      t += __shfl_xor(t, 2, 16);
      t += __shfl_xor(t, 4, 16);
      t += __shfl_xor(t, 8, 16);
      const float inv = 1.0f / t;
      const int row = mt * 16 + quad * 4 + r;
      Ps[row * 72 +  0 + l16] = f2bf(e0 * inv);   // overlays Q/K (frags already in regs)
      Ps[row * 72 + 16 + l16] = f2bf(e1 * inv);
      Ps[row * 72 + 32 + l16] = f2bf(e2 * inv);
      Ps[row * 72 + 48 + l16] = f2bf(e3 * inv);
    }

  // ---- Phase 3: O = P V  ([64x64] @ [64x32]) ----
  f32x4 aO[4][2] = {};
#pragma unroll
  for (int ks = 0; ks < 2; ++ks) {
    const int ko = ks * 32 + quad * 8;
    bf16x8 pf[4], vf[2];
#pragma unroll
    for (int mt = 0; mt < 4; ++mt) pf[mt] = *(const bf16x8*)&Ps[(mt * 16 + l16) * 72 + ko];
#pragma unroll
    for (int nt = 0; nt < 2; ++nt) vf[nt] = *(const bf16x8*)&Vt[(nt * 16 + l16) * 72 + ko];
#pragma unroll
    for (int mt = 0; mt < 4; ++mt)
#pragma unroll
      for (int nt = 0; nt < 2; ++nt)
        aO[mt][nt] = __builtin_amdgcn_mfma_f32_16x16x32_bf16(pf[mt], vf[nt], aO[mt][nt], 0, 0, 0);
  }
  __syncthreads();   // all Vt reads done -> Os may overlay
  // write O (head-concat) -> Os[token][128] in Xs region
#pragma unroll
  for (int mt = 0; mt < 4; ++mt)
#pragma unroll
    for (int nt = 0; nt < 2; ++nt)
#pragma unroll
      for (int r = 0; r < 4; ++r)
        Xs[(mt * 16 + quad * 4 + r) * 136 + wv * 32 + nt * 16 + l16] = f2bf(aO[mt][nt][r]);
  __syncthreads();

  // ---- Phase 4: proj: out = Os[64x128] @ wproj[128x128] + b; scatter-store ----
  f32x4 aP[4][2] = {};
#pragma unroll
  for (int ks = 0; ks < 4; ++ks) {
    const int ko = ks * 32 + quad * 8;
    bf16x8 af[4];
#pragma unroll
    for (int mt = 0; mt < 4; ++mt) af[mt] = *(const bf16x8*)&Xs[(mt * 16 + l16) * 136 + ko];
#pragma unroll
    for (int nt = 0; nt < 2; ++nt) {
      const int n = wv * 32 + nt * 16 + l16;
      const bf16x8 bw = *(const bf16x8*)&wT[(384 + n) * 128 + ko];
#pragma unroll
      for (int mt = 0; mt < 4; ++mt)
        aP[mt][nt] = __builtin_amdgcn_mfma_f32_16x16x32_bf16(af[mt], bw, aP[mt][nt], 0, 0, 0);
    }
  }
#pragma unroll
  for (int nt = 0; nt < 2; ++nt) {
    const int c = wv * 32 + nt * 16 + l16;
    const float bias = bproj[c];
#pragma unroll
    for (int mt = 0; mt < 4; ++mt) {
      const int tb  = mt * 16 + quad * 4;        // 4 consecutive tokens = same h, w..w+3
      const int ty  = tb >> 3;
      const int txb = tb & 7;
      const int hh  = (wy * 8 + ty + 4) & 255;   // inverse roll(+4)
      const int ww  = (wx * 8 + txb + 4) & 255;  // multiple of 4 -> aligned, no wrap
      float4 v;
      v.x = aP[mt][nt][0] + bias;
      v.y = aP[mt][nt][1] + bias;
      v.z = aP[mt][nt][2] + bias;
      v.w = aP[mt][nt][3] + bias;
      *(float4*)(out + ((b * 128 + c) * 256 + hh) * 256 + ww) = v;
    }
  }
}

extern "C" void kernel_launch(void* const* d_in, const int* in_sizes, int n_in,
                              void* d_out, int out_size, void* d_ws, size_t ws_size,
                              hipStream_t stream) {
  const float* x     = (const float*)d_in[0];
  const float* wqkv  = (const float*)d_in[1];
  const float* wproj = (const float*)d_in[2];
  const float* bp    = (const float*)d_in[3];
  unsigned short* wT = (unsigned short*)d_ws;    // 65536 bf16 = 131072 B

  prep_kernel<<<256, 256, 0, stream>>>(wqkv, wproj, wT);
  swin_kernel<<<8192, 256, 0, stream>>>(x, wT, bp, (float*)d_out);
}

// Round 2
// 605.085 us; speedup vs baseline: 1.2810x; 1.2810x over previous
//
#include <hip/hip_runtime.h>

// SwinStyleAttention fused kernel — MI355X gfx950, round 2.
// Block = 1 window (64 tok x 128 ch), 4 waves = 4 heads. All MFMA 16x16x32 bf16.
// Strategy: frag-native LDS layouts, transposed Q/K/O so C-layout 'r' index is
// LDS-contiguous (b64 staging writes, b128 frag reads, conflict-free),
// S^T softmax (8 shfls/wave), 1/sum folded into epilogue, XCD swizzle.

typedef __attribute__((ext_vector_type(8))) short bf16x8;   // 8 bf16 = 4 VGPRs
typedef __attribute__((ext_vector_type(4))) float f32x4;    // 16x16 MFMA acc

__device__ __forceinline__ unsigned f2bfbits(float f) {     // round-half-up
  union { float f; unsigned u; } v; v.f = f;
  return (v.u + 0x8000u) >> 16;
}
// pack two floats -> dword of 2 bf16 (lo, hi) in 3 VALU ops
__device__ __forceinline__ unsigned pk2(float lo, float hi) {
  union { float f; unsigned u; } a, b; a.f = lo; b.f = hi;
  return __builtin_amdgcn_perm(b.u + 0x8000u, a.u + 0x8000u, 0x07060302u);
}

__device__ __forceinline__ unsigned short f2bf_rne(float f) {
  union { float f; unsigned u; } v; v.f = f;
  return (unsigned short)((v.u + 0x7FFFu + ((v.u >> 16) & 1u)) >> 16);
}

// Weight prep: wqkvT[384][128] then wprojT[128][128], bf16, row n = out col.
__global__ void prep_kernel(const float* __restrict__ wqkv,
                            const float* __restrict__ wproj,
                            unsigned short* __restrict__ wT) {
  const int idx = blockIdx.x * 256 + (int)threadIdx.x;   // 65536 total
  if (idx < 384 * 128) {
    const int n = idx >> 7, k = idx & 127;
    wT[idx] = f2bf_rne(wqkv[k * 384 + n]);
  } else {
    const int j = idx - 384 * 128;
    const int n = j >> 7, k = j & 127;
    wT[idx] = f2bf_rne(wproj[k * 128 + n]);
  }
}

// LDS (shorts, 24576 = 48 KiB):
//  XF  [0,8192):     X frags [kc16][tok64][j8] -> per-head QF/P slots (wv*2048) -> Os
//  KB  [8192,16384): per-head KF [kc4][tok64][j8]
//  VB  [16384,24576): per-head VF [kcv8][dh32][j8]
__global__ void __launch_bounds__(256, 3)
swin_kernel(const float* __restrict__ x, const unsigned short* __restrict__ wT,
            const float* __restrict__ bproj, float* __restrict__ out) {
  __shared__ unsigned short SM[24576];

  const int bid = blockIdx.x;
  const int win = (bid & 7) * 1024 + (bid >> 3);   // XCD swizzle: image per XCD
  const int b  = win >> 10;
  const int wy = (win >> 5) & 31;
  const int wx = win & 31;
  const int tid  = (int)threadIdx.x;
  const int lane = tid & 63;
  const int wv   = tid >> 6;        // wave id == head id
  const int q    = lane >> 4;       // quad
  const int l16  = lane & 15;
  const int qh   = q >> 1, ql = q & 1;

  unsigned short* XF  = SM;
  unsigned short* KFh = SM + 8192  + wv * 2048;
  unsigned short* VFh = SM + 16384 + wv * 2048;
  unsigned short* QFh = XF + wv * 2048;    // Q frags, later P half-swap

  // ---- Phase 0: gather shifted window -> XF frag layout ----
  {
    const int t4 = tid & 15, cw = tid >> 4;      // cw 0..15
    const int ty = t4 >> 1, txb = (t4 & 1) << 2;
    const int hh = (wy * 8 + ty + 4) & 255;      // roll(-4)
    const int ww = (wx * 8 + txb + 4) & 255;     // mult of 4 -> no wrap in float4
    const float* src = x + ((b * 128) * 256 + hh) * 256 + ww;
    const int t0 = t4 << 2;
#pragma unroll
    for (int i = 0; i < 8; ++i) {
      const int c = i * 16 + cw;
      const float4 v = *(const float4*)(src + c * 65536);
      unsigned short* p = &XF[(c >> 3) * 512 + t0 * 8 + (c & 7)];
      p[0]  = (unsigned short)f2bfbits(v.x);
      p[8]  = (unsigned short)f2bfbits(v.y);
      p[16] = (unsigned short)f2bfbits(v.z);
      p[24] = (unsigned short)f2bfbits(v.w);
    }
  }
  __syncthreads();   // B1

  // ---- Pass A: QT,KT = W^T X^T  (m=dh_local 2 tiles, n=tok 4 tiles, k=C) ----
  f32x4 aQT[2][4] = {}; f32x4 aKT[2][4] = {};
#pragma unroll
  for (int ks = 0; ks < 4; ++ks) {
    const int ko = ks * 32 + q * 8;
    bf16x8 xb[4];
#pragma unroll
    for (int nt = 0; nt < 4; ++nt)
      xb[nt] = *(const bf16x8*)&XF[(ks * 4 + q) * 512 + (nt * 16 + l16) * 8];
#pragma unroll
    for (int mA = 0; mA < 2; ++mA) {
      const int row = wv * 32 + mA * 16 + l16;
      const bf16x8 wq = *(const bf16x8*)&wT[row * 128 + ko];
      const bf16x8 wk = *(const bf16x8*)&wT[(128 + row) * 128 + ko];
#pragma unroll
      for (int nt = 0; nt < 4; ++nt) {
        aQT[mA][nt] = __builtin_amdgcn_mfma_f32_16x16x32_bf16(wq, xb[nt], aQT[mA][nt], 0, 0, 0);
        aKT[mA][nt] = __builtin_amdgcn_mfma_f32_16x16x32_bf16(wk, xb[nt], aKT[mA][nt], 0, 0, 0);
      }
    }
  }
  // stage KF (region fresh, own-wave): dh = 16mA+8qh+4ql+r -> kc=2mA+qh, j=4ql+r
#pragma unroll
  for (int mA = 0; mA < 2; ++mA)
#pragma unroll
    for (int nt = 0; nt < 4; ++nt) {
      uint2 w;
      w.x = pk2(aKT[mA][nt][0], aKT[mA][nt][1]);
      w.y = pk2(aKT[mA][nt][2], aKT[mA][nt][3]);
      *(uint2*)&KFh[(mA * 2 + qh) * 512 + (nt * 16 + l16) * 8 + ql * 4] = w;
    }

  // ---- Pass B: V = X Wv (m=tok 4 tiles, n=dh 2 tiles) ----
  f32x4 aV[4][2] = {};
#pragma unroll
  for (int ks = 0; ks < 4; ++ks) {
    const int ko = ks * 32 + q * 8;
    bf16x8 af[4];
#pragma unroll
    for (int mt = 0; mt < 4; ++mt)
      af[mt] = *(const bf16x8*)&XF[(ks * 4 + q) * 512 + (mt * 16 + l16) * 8];
#pragma unroll
    for (int nt = 0; nt < 2; ++nt) {
      const bf16x8 bv = *(const bf16x8*)&wT[(256 + wv * 32 + nt * 16 + l16) * 128 + ko];
#pragma unroll
      for (int mt = 0; mt < 4; ++mt)
        aV[mt][nt] = __builtin_amdgcn_mfma_f32_16x16x32_bf16(af[mt], bv, aV[mt][nt], 0, 0, 0);
    }
  }
  // stage VF: tok = 16mt+8qh+4ql+r -> kcv=2mt+qh, j=4ql+r; dh=16nt+l16
#pragma unroll
  for (int mt = 0; mt < 4; ++mt)
#pragma unroll
    for (int nt = 0; nt < 2; ++nt) {
      uint2 w;
      w.x = pk2(aV[mt][nt][0], aV[mt][nt][1]);
      w.y = pk2(aV[mt][nt][2], aV[mt][nt][3]);
      *(uint2*)&VFh[(mt * 2 + qh) * 256 + (nt * 16 + l16) * 8 + ql * 4] = w;
    }
  __syncthreads();   // B2: all XF reads done -> QF may overlay

  // stage QF (pre-scaled)
  constexpr float SC = 0.17677669529663687f;   // 32^-0.5
#pragma unroll
  for (int mA = 0; mA < 2; ++mA)
#pragma unroll
    for (int nt = 0; nt < 4; ++nt) {
      uint2 w;
      w.x = pk2(aQT[mA][nt][0] * SC, aQT[mA][nt][1] * SC);
      w.y = pk2(aQT[mA][nt][2] * SC, aQT[mA][nt][3] * SC);
      *(uint2*)&QFh[(mA * 2 + qh) * 512 + (nt * 16 + l16) * 8 + ql * 4] = w;
    }

  // ---- S^T = K Q^T : A=K-frag, B=Q-frag, single K=32 step ----
  bf16x8 kf[4], qf[4];
#pragma unroll
  for (int t = 0; t < 4; ++t) {
    kf[t] = *(const bf16x8*)&KFh[q * 512 + (t * 16 + l16) * 8];
    qf[t] = *(const bf16x8*)&QFh[q * 512 + (t * 16 + l16) * 8];
  }
  f32x4 aS[4][4] = {};
#pragma unroll
  for (int mt = 0; mt < 4; ++mt)
#pragma unroll
    for (int nt = 0; nt < 4; ++nt)
      aS[mt][nt] = __builtin_amdgcn_mfma_f32_16x16x32_bf16(kf[mt], qf[nt], aS[mt][nt], 0, 0, 0);
  // lane holds S[tq=16nt+l16][tk=16mt+4q+r]

  // ---- softmax (no max-subtract; 1/sum deferred to epilogue) ----
#pragma unroll
  for (int mt = 0; mt < 4; ++mt)
#pragma unroll
    for (int nt = 0; nt < 4; ++nt)
#pragma unroll
      for (int r = 0; r < 4; ++r)
        aS[mt][nt][r] = __expf(aS[mt][nt][r]);
  float inv[4];
#pragma unroll
  for (int nt = 0; nt < 4; ++nt) {
    float s = 0.f;
#pragma unroll
    for (int mt = 0; mt < 4; ++mt)
#pragma unroll
      for (int r = 0; r < 4; ++r) s += aS[mt][nt][r];
    s += __shfl_xor(s, 16);
    s += __shfl_xor(s, 32);
    inv[nt] = 1.0f / s;
  }

  // ---- O^T = V^T P^T, tk in 2 halves; P half-swapped into dead Q slot ----
  f32x4 aOT[2][4] = {};
#pragma unroll
  for (int h = 0; h < 2; ++h) {
#pragma unroll
    for (int mh = 0; mh < 2; ++mh) {
      const int mt = h * 2 + mh;
#pragma unroll
      for (int nt = 0; nt < 4; ++nt) {
        uint2 w;
        w.x = pk2(aS[mt][nt][0], aS[mt][nt][1]);
        w.y = pk2(aS[mt][nt][2], aS[mt][nt][3]);
        *(uint2*)&QFh[(mh * 2 + qh) * 512 + (nt * 16 + l16) * 8 + ql * 4] = w;
      }
    }
    bf16x8 pf[4], vf[2];
#pragma unroll
    for (int t = 0; t < 4; ++t)
      pf[t] = *(const bf16x8*)&QFh[q * 512 + (t * 16 + l16) * 8];
#pragma unroll
    for (int nb = 0; nb < 2; ++nb)
      vf[nb] = *(const bf16x8*)&VFh[(h * 4 + q) * 256 + (nb * 16 + l16) * 8];
#pragma unroll
    for (int mo = 0; mo < 2; ++mo)
#pragma unroll
      for (int np = 0; np < 4; ++np)
        aOT[mo][np] = __builtin_amdgcn_mfma_f32_16x16x32_bf16(vf[mo], pf[np], aOT[mo][np], 0, 0, 0);
  }
  __syncthreads();   // B3: all P/Q-slot reads done -> Os may overlay XF

  // ---- stage Os (normalized): c = wv*32+16mo+8qh+4ql+r, tok = 16np+l16 ----
#pragma unroll
  for (int mo = 0; mo < 2; ++mo)
#pragma unroll
    for (int np = 0; np < 4; ++np) {
      const float s = inv[np];
      uint2 w;
      w.x = pk2(aOT[mo][np][0] * s, aOT[mo][np][1] * s);
      w.y = pk2(aOT[mo][np][2] * s, aOT[mo][np][3] * s);
      *(uint2*)&XF[(wv * 4 + mo * 2 + qh) * 512 + (np * 16 + l16) * 8 + ql * 4] = w;
    }
  __syncthreads();   // B4

  // ---- proj: out = Os[64x128] @ wproj + b ----
  f32x4 aP[4][2] = {};
#pragma unroll
  for (int ks = 0; ks < 4; ++ks) {
    const int ko = ks * 32 + q * 8;
    bf16x8 af[4];
#pragma unroll
    for (int mt = 0; mt < 4; ++mt)
      af[mt] = *(const bf16x8*)&XF[(ks * 4 + q) * 512 + (mt * 16 + l16) * 8];
#pragma unroll
    for (int nt = 0; nt < 2; ++nt) {
      const bf16x8 bw = *(const bf16x8*)&wT[(384 + wv * 32 + nt * 16 + l16) * 128 + ko];
#pragma unroll
      for (int mt = 0; mt < 4; ++mt)
        aP[mt][nt] = __builtin_amdgcn_mfma_f32_16x16x32_bf16(af[mt], bw, aP[mt][nt], 0, 0, 0);
    }
  }
#pragma unroll
  for (int nt = 0; nt < 2; ++nt) {
    const int c = wv * 32 + nt * 16 + l16;
    const float bias = bproj[c];
#pragma unroll
    for (int mt = 0; mt < 4; ++mt) {
      const int tb  = mt * 16 + q * 4;        // 4 consecutive tokens, same h row
      const int ty  = tb >> 3;
      const int txb = tb & 7;
      const int hh  = (wy * 8 + ty + 4) & 255;   // inverse roll(+4)
      const int ww  = (wx * 8 + txb + 4) & 255;
      float4 v;
      v.x = aP[mt][nt][0] + bias;
      v.y = aP[mt][nt][1] + bias;
      v.z = aP[mt][nt][2] + bias;
      v.w = aP[mt][nt][3] + bias;
      *(float4*)(out + ((b * 128 + c) * 256 + hh) * 256 + ww) = v;
    }
  }
}

extern "C" void kernel_launch(void* const* d_in, const int* in_sizes, int n_in,
                              void* d_out, int out_size, void* d_ws, size_t ws_size,
                              hipStream_t stream) {
  const float* x     = (const float*)d_in[0];
  const float* wqkv  = (const float*)d_in[1];
  const float* wproj = (const float*)d_in[2];
  const float* bp    = (const float*)d_in[3];
  unsigned short* wT = (unsigned short*)d_ws;    // 65536 bf16 = 131072 B

  prep_kernel<<<256, 256, 0, stream>>>(wqkv, wproj, wT);
  swin_kernel<<<8192, 256, 0, stream>>>(x, wT, bp, (float*)d_out);
}